// Round 6
// baseline (508.436 us; speedup 1.0000x reference)
//
#include <hip/hip_runtime.h>
#include <hip/hip_bf16.h>

// ---------------------------------------------------------------------------
// SemanticComposite: attention-like mix + 3-gate combine.
// R6 = R5 with ONE change: k_attn __launch_bounds__(1024,4) -> (1024,1).
//   R5's (1024,4) empirically capped VGPR at 64 -> spilled O accumulators
//   (FETCH+WRITE 756 MB scratch traffic, 408 us). (1024,1) keeps the
//   16-wave/CU occupancy + VSWZ conflict fix without the register cap.
// ---------------------------------------------------------------------------

typedef unsigned short u16;
typedef unsigned int   u32;
typedef u16   u16x8 __attribute__((ext_vector_type(8)));
typedef u16   u16x4 __attribute__((ext_vector_type(4)));
typedef short s16x8 __attribute__((ext_vector_type(8)));
typedef float f32x4 __attribute__((ext_vector_type(4)));

#define MFMA16(a,b,c) __builtin_amdgcn_mfma_f32_16x16x32_bf16( \
    __builtin_bit_cast(s16x8,(a)), __builtin_bit_cast(s16x8,(b)), (c), 0, 0, 0)

static __device__ __forceinline__ u16 f2bf(float f) {
  __hip_bfloat16 h = __float2bfloat16(f);
  return *reinterpret_cast<u16*>(&h);
}

#define NB   8
#define NS   2048
#define NF   256
#define NR   (NB*NS)          // 16384 rows

// vt swizzle: spreads both pr-clusters and a-clusters across banks.
#define VSWZ(f) ((((f) & 7) << 4) ^ ((((f) >> 3) & 3) << 5))

// ---------------- prep: qb = bf16(x*wc), xb = bf16(x), bvec = x.wb ---------
__global__ __launch_bounds__(256) void k_prep(const float* __restrict__ x,
                                              const float* __restrict__ attw,
                                              u16* __restrict__ qb,
                                              u16* __restrict__ xb,
                                              float* __restrict__ bvec) {
  const int lane = threadIdx.x & 63, w = threadIdx.x >> 6;
  const int row = blockIdx.x * 4 + w;                 // 0..16383
  const float4 xv = *reinterpret_cast<const float4*>(x + (size_t)row * NF + lane * 4);
  const float4 wc = *reinterpret_cast<const float4*>(attw + 2 * NF + lane * 4);
  const float4 wb = *reinterpret_cast<const float4*>(attw + NF + lane * 4);
  u16x4 q, xq;
  q[0] = f2bf(xv.x * wc.x); q[1] = f2bf(xv.y * wc.y);
  q[2] = f2bf(xv.z * wc.z); q[3] = f2bf(xv.w * wc.w);
  xq[0] = f2bf(xv.x); xq[1] = f2bf(xv.y); xq[2] = f2bf(xv.z); xq[3] = f2bf(xv.w);
  *reinterpret_cast<u16x4*>(qb + (size_t)row * NF + lane * 4) = q;
  *reinterpret_cast<u16x4*>(xb + (size_t)row * NF + lane * 4) = xq;
  float s = xv.x * wb.x + xv.y * wb.y + xv.z * wb.z + xv.w * wb.w;
  #pragma unroll
  for (int m = 1; m < 64; m <<= 1) s += __shfl_xor(s, m, 64);
  if (lane == 0) bvec[row] = s;
}

// ---------------- weight repack to B-fragment-linear bf16 ------------------
// wfrag[w][ks][nt][lane][i] = W[16*nt + (lane&15)][32*ks + 8*(lane>>4) + i]
__global__ __launch_bounds__(64) void k_wrep(const float* __restrict__ zw,
                                             const float* __restrict__ rw,
                                             const float* __restrict__ fw,
                                             u16* __restrict__ wfrag) {
  const int lane = threadIdx.x & 63;
  const int idx = blockIdx.x;                   // 0..767
  const int w = idx >> 8, rem = idx & 255, ks = rem >> 4, nt = rem & 15;
  const float* W = (w == 0) ? zw : ((w == 1) ? rw : fw);
  const int n = lane & 15, g = lane >> 4;
  const float* src = W + (size_t)(nt * 16 + n) * 512 + ks * 32 + g * 8;
  u16x8 o;
  #pragma unroll
  for (int i = 0; i < 8; ++i) o[i] = f2bf(src[i]);
  *reinterpret_cast<u16x8*>(wfrag + ((size_t)(w * 256 + ks * 16 + nt) * 64 + lane) * 8) = o;
}

// ---------------- flash attention (R6) -------------------------------------
// grid 256 = (itile, b), b = blockIdx%8 (XCD swizzle). 1024 threads = 16
// waves: wr = w&3 -> 16-row quarter; wg = w>>2 -> j-quarter (512 j, 8 jtt).
// LDS 163840 B: vt[4 grp][256 f][64 j] bf16 swz (131072) + pl[16 wave]
// [16 row][64 j] bf16 swz (32768). Merge: Of0/Of1 alias vt, ML aliases pl.
__global__ __launch_bounds__(1024, 1) void k_attn(const u16* __restrict__ qb,
                                                  const u16* __restrict__ xb,
                                                  const float* __restrict__ bvec,
                                                  u16* __restrict__ attnb) {
  extern __shared__ u16 lds[];
  const int tid = threadIdx.x;
  const int w = tid >> 6, lane = tid & 63;
  const int wr = w & 3, wg = w >> 2;
  const int n = lane & 15, g = lane >> 4;
  const int b = blockIdx.x & 7, itile = blockIdx.x >> 3;
  const int i0 = itile * 64;
  const size_t xbase = (size_t)b * (NS * NF);

  char* vt = reinterpret_cast<char*>(lds) + wg * 32768;
  char* pl = reinterpret_cast<char*>(lds) + 131072 + w * 2048;

  // Q fragments for this wave's 16 rows: 8 ks chunks
  u16x8 qf[8];
  {
    const u16* qrow = qb + xbase + (size_t)(i0 + 16 * wr + n) * NF + 8 * g;
    #pragma unroll
    for (int ks = 0; ks < 8; ++ks) qf[ks] = *reinterpret_cast<const u16x8*>(qrow + 32 * ks);
  }

  f32x4 O[16];
  #pragma unroll
  for (int nf = 0; nf < 16; ++nf) O[nf] = 0.f;
  float mrow[4], lrow[4];
  #pragma unroll
  for (int r = 0; r < 4; ++r) { mrow[r] = -__builtin_inff(); lrow[r] = 0.f; }

  for (int jtt = 0; jtt < 8; ++jtt) {
    const int j0 = wg * 512 + jtt * 64;
    // ---- stage V^T tile [256 f][64 j] (group = 256 threads, pair-packed) --
    {
      const int tg = tid & 255;
      const int pr = tg >> 3, a = tg & 7;            // j-pair 0..31, f-chunk
      #pragma unroll
      for (int it = 0; it < 4; ++it) {
        const int c = 8 * (a + 8 * it);
        const u16* r0 = xb + xbase + (size_t)(j0 + 2 * pr) * NF + c;
        u16x8 v0 = *reinterpret_cast<const u16x8*>(r0);
        u16x8 v1 = *reinterpret_cast<const u16x8*>(r0 + NF);
        #pragma unroll
        for (int i = 0; i < 8; ++i) {
          const int f = c + i;
          const u32 pk = (u32)v0[i] | ((u32)v1[i] << 16);
          const int byte = (f * 128 + 4 * pr) ^ VSWZ(f);
          *reinterpret_cast<u32*>(vt + byte) = pk;
        }
      }
    }
    __syncthreads();
    // ---- QK^T: 4 nf x 8 ks, K B-frags direct from global (L1/L2) ----------
    f32x4 sc[4];
    #pragma unroll
    for (int nf = 0; nf < 4; ++nf) {
      f32x4 acc = 0.f;
      const u16* krow = xb + xbase + (size_t)(j0 + 16 * nf + n) * NF + 8 * g;
      __builtin_amdgcn_s_setprio(1);
      #pragma unroll
      for (int ks = 0; ks < 8; ++ks) {
        u16x8 kf = *reinterpret_cast<const u16x8*>(krow + 32 * ks);
        acc = MFMA16(qf[ks], kf, acc);
      }
      __builtin_amdgcn_s_setprio(0);
      const float bv = bvec[b * NS + j0 + 16 * nf + n];
      #pragma unroll
      for (int r = 0; r < 4; ++r) sc[nf][r] = acc[r] + bv;
    }
    // ---- online softmax (rows = 4g+r, cols = n across 4 nf) ---------------
    float pmax[4];
    #pragma unroll
    for (int r = 0; r < 4; ++r) {
      float v = fmaxf(fmaxf(sc[0][r], sc[1][r]), fmaxf(sc[2][r], sc[3][r]));
      #pragma unroll
      for (int m = 1; m < 16; m <<= 1) v = fmaxf(v, __shfl_xor(v, m, 64));
      pmax[r] = v;
    }
    int needi = 0;
    #pragma unroll
    for (int r = 0; r < 4; ++r) needi |= (pmax[r] > mrow[r] + 8.0f) ? 1 : 0;
    if (__any(needi)) {               // T13 defer-max
      #pragma unroll
      for (int r = 0; r < 4; ++r) {
        const float mn = fmaxf(mrow[r], pmax[r]);
        const float scl = __expf(mrow[r] - mn);
        mrow[r] = mn; lrow[r] *= scl;
        #pragma unroll
        for (int nf = 0; nf < 16; ++nf) O[nf][r] *= scl;
      }
    }
    float p[4][4];
    #pragma unroll
    for (int nf = 0; nf < 4; ++nf)
      #pragma unroll
      for (int r = 0; r < 4; ++r) p[nf][r] = __expf(sc[nf][r] - mrow[r]);
    #pragma unroll
    for (int r = 0; r < 4; ++r) {
      float s = p[0][r] + p[1][r] + p[2][r] + p[3][r];
      #pragma unroll
      for (int m = 1; m < 16; m <<= 1) s += __shfl_xor(s, m, 64);
      lrow[r] += s;
    }
    // ---- P -> pl (swizzled [16 row][64 j]) -> A-frags ---------------------
    #pragma unroll
    for (int nf = 0; nf < 4; ++nf)
      #pragma unroll
      for (int r = 0; r < 4; ++r) {
        const int row = 4 * g + r, col = 16 * nf + n;
        const int byte = (row * 128 + 2 * col) ^ ((row & 7) << 4);
        *reinterpret_cast<u16*>(pl + byte) = f2bf(p[nf][r]);
      }
    // ---- PV: 2 ks2 x 16 nf ------------------------------------------------
    #pragma unroll
    for (int ks2 = 0; ks2 < 2; ++ks2) {
      const int pbyte = (n * 128 + 16 * g + 64 * ks2) ^ ((n & 7) << 4);
      u16x8 pa = *reinterpret_cast<const u16x8*>(pl + pbyte);
      __builtin_amdgcn_s_setprio(1);
      #pragma unroll
      for (int nf16 = 0; nf16 < 16; ++nf16) {
        const int f = 16 * nf16 + n;
        const int vbyte = (f * 128 + 16 * g + 64 * ks2) ^ VSWZ(f);
        u16x8 vf = *reinterpret_cast<const u16x8*>(vt + vbyte);
        O[nf16] = MFMA16(pa, vf, O[nf16]);
      }
      __builtin_amdgcn_s_setprio(0);
    }
    __syncthreads();
  }

  // ---- 4-way flash merge across j-quarters --------------------------------
  // ML[4 wg][64 row][2] f32 aliases pl region; Of0/Of1 alias vt.
  float* ML = reinterpret_cast<float*>(reinterpret_cast<char*>(lds) + 131072);
  if (n == 0) {
    #pragma unroll
    for (int r = 0; r < 4; ++r) {
      const int row = 16 * wr + 4 * g + r;
      ML[(wg * 64 + row) * 2]     = mrow[r];
      ML[(wg * 64 + row) * 2 + 1] = lrow[r];
    }
  }
  __syncthreads();                                   // B1
  float fac[4], rL[4];
  #pragma unroll
  for (int r = 0; r < 4; ++r) {
    const int row = 16 * wr + 4 * g + r;
    float M = -__builtin_inff();
    #pragma unroll
    for (int q = 0; q < 4; ++q) M = fmaxf(M, ML[(q * 64 + row) * 2]);
    float L = 0.f;
    #pragma unroll
    for (int q = 0; q < 4; ++q) L += ML[(q * 64 + row) * 2 + 1] * __expf(ML[(q * 64 + row) * 2] - M);
    fac[r] = __expf(mrow[r] - M);
    rL[r]  = 1.0f / L;
  }
  char* Of0 = reinterpret_cast<char*>(lds);
  char* Of1 = reinterpret_cast<char*>(lds) + 65536;
  #define OBYTE(row, col) (((row) * 1024 + 4 * (col)) ^ (((row) & 12) << 3))
  if (wg == 1 || wg == 3) {
    char* Ofx = (wg == 1) ? Of0 : Of1;
    #pragma unroll
    for (int nf16 = 0; nf16 < 16; ++nf16)
      #pragma unroll
      for (int r = 0; r < 4; ++r) {
        const int row = 16 * wr + 4 * g + r, col = 16 * nf16 + n;
        *reinterpret_cast<float*>(Ofx + OBYTE(row, col)) = O[nf16][r] * fac[r];
      }
  }
  __syncthreads();                                   // B2
  if (wg == 0) {
    #pragma unroll
    for (int nf16 = 0; nf16 < 16; ++nf16)
      #pragma unroll
      for (int r = 0; r < 4; ++r) {
        const int row = 16 * wr + 4 * g + r, col = 16 * nf16 + n;
        O[nf16][r] = O[nf16][r] * fac[r] +
                     *reinterpret_cast<const float*>(Of0 + OBYTE(row, col));
      }
  } else if (wg == 2) {
    #pragma unroll
    for (int nf16 = 0; nf16 < 16; ++nf16)
      #pragma unroll
      for (int r = 0; r < 4; ++r) {
        const int row = 16 * wr + 4 * g + r, col = 16 * nf16 + n;
        float v = O[nf16][r] * fac[r] +
                  *reinterpret_cast<const float*>(Of1 + OBYTE(row, col));
        *reinterpret_cast<float*>(Of1 + OBYTE(row, col)) = v;
      }
  }
  __syncthreads();                                   // B3
  if (wg == 0) {
    #pragma unroll
    for (int nf16 = 0; nf16 < 16; ++nf16)
      #pragma unroll
      for (int r = 0; r < 4; ++r) {
        const int row = 16 * wr + 4 * g + r, col = 16 * nf16 + n;
        const float v = (O[nf16][r] +
            *reinterpret_cast<const float*>(Of1 + OBYTE(row, col))) * rL[r];
        attnb[xbase + (size_t)(i0 + row) * NF + col] = f2bf(v);
      }
  }
}

// ---------------- fused gate GEMMs + epilogue ------------------------------
// grid 1024 x 256 thr: block = 16 rows; wave w -> col quarter (nt = 4w+nt2).
__global__ __launch_bounds__(256, 4) void k_gate(const u16* __restrict__ xb,
                                                 const u16* __restrict__ attnb,
                                                 const float* __restrict__ x,
                                                 const float* __restrict__ zb,
                                                 const float* __restrict__ rb,
                                                 const float* __restrict__ fb,
                                                 const u16* __restrict__ wfrag,
                                                 float* __restrict__ out) {
  const int tid = threadIdx.x, w = tid >> 6, lane = tid & 63;
  const int m0 = blockIdx.x * 16;
  const int n = lane & 15, g = lane >> 4;

  u16x8 af[16];
  {
    const int row = m0 + n;
    const u16* xr = xb + (size_t)row * NF + 8 * g;
    #pragma unroll
    for (int ks = 0; ks < 8; ++ks) af[ks] = *reinterpret_cast<const u16x8*>(xr + 32 * ks);
    const u16* ar = attnb + (size_t)row * NF + 8 * g;
    #pragma unroll
    for (int ks = 0; ks < 8; ++ks) af[8 + ks] = *reinterpret_cast<const u16x8*>(ar + 32 * ks);
  }
  #pragma unroll
  for (int nt2 = 0; nt2 < 4; ++nt2) {
    const int nt = 4 * w + nt2;
    const int col = 16 * nt + n;
    f32x4 za = zb[col], ra = rb[col], fa = fb[col];
    #pragma unroll
    for (int ks = 0; ks < 16; ++ks) {
      const size_t base = ((size_t)(ks * 16 + nt) * 64 + lane) * 8;
      u16x8 bz  = *reinterpret_cast<const u16x8*>(wfrag + base);
      u16x8 br  = *reinterpret_cast<const u16x8*>(wfrag + (size_t)256 * 64 * 8 + base);
      u16x8 bff = *reinterpret_cast<const u16x8*>(wfrag + (size_t)512 * 64 * 8 + base);
      za = MFMA16(af[ks], bz, za);
      ra = MFMA16(af[ks], br, ra);
      fa = MFMA16(af[ks], bff, fa);
    }
    #pragma unroll
    for (int r = 0; r < 4; ++r) {
      const int row = m0 + 4 * g + r;
      const float xv = x[(size_t)row * NF + col];
      const float zv = 2.f / (1.f + __expf(-2.f * za[r])) - 1.f;  // tanh
      const float rv = 1.f / (1.f + __expf(-ra[r]));
      const float fv = 1.f / (1.f + __expf(-fa[r]));
      out[(size_t)row * NF + col] = rv * xv + fv * zv;
    }
  }
}

// ---------------------------------------------------------------------------
extern "C" void kernel_launch(void* const* d_in, const int* in_sizes, int n_in,
                              void* d_out, int out_size, void* d_ws, size_t ws_size,
                              hipStream_t stream) {
  const float* x    = (const float*)d_in[0];
  const float* attw = (const float*)d_in[1];
  const float* zw   = (const float*)d_in[2];
  const float* zb   = (const float*)d_in[3];
  const float* rw   = (const float*)d_in[4];
  const float* rb   = (const float*)d_in[5];
  const float* fw   = (const float*)d_in[6];
  const float* fb   = (const float*)d_in[7];
  float* out = (float*)d_out;

  char* ws = (char*)d_ws;
  u16*   qb    = (u16*)(ws);                       //  8 MB
  u16*   xbb   = (u16*)(ws + 8388608);             //  8 MB
  u16*   attnb = (u16*)(ws + 16777216);            //  8 MB
  float* bvec  = (float*)(ws + 25165824);          // 64 KB
  u16*   wfrag = (u16*)(ws + 25231360);            // 768 KB

  (void)hipFuncSetAttribute((const void*)k_attn,
      hipFuncAttributeMaxDynamicSharedMemorySize, 163840);

  k_prep<<<NR / 4, 256, 0, stream>>>(x, attw, qb, xbb, bvec);
  k_wrep<<<768, 64, 0, stream>>>(zw, rw, fw, wfrag);
  k_attn<<<256, 1024, 163840, stream>>>(qb, xbb, bvec, attnb);
  k_gate<<<1024, 256, 0, stream>>>(xbb, attnb, x, zb, rb, fb, wfrag, out);
}

// Round 7
// 309.339 us; speedup vs baseline: 1.6436x; 1.6436x over previous
//
#include <hip/hip_runtime.h>
#include <hip/hip_bf16.h>

// ---------------------------------------------------------------------------
// SemanticComposite: attention-like mix + 3-gate combine.
// R7: cross-block flash split. k_attn grid 512 (j-half per block), 512 thr,
//     LDS 81920 B exactly -> 2 blocks/CU (4 waves/SIMD) with R4's spill-free
//     wave state (VGPR ~116). Blocks write normalized bf16 partials + (M,L);
//     k_amerge combines the two halves in place.
// LESSON (R5/R6): 1024-thr blocks are pinned to 64+64 VGPR on gfx950 ->
//     this kernel's wave state spills. Never use 1024-thr blocks here.
// ---------------------------------------------------------------------------

typedef unsigned short u16;
typedef unsigned int   u32;
typedef u16   u16x8 __attribute__((ext_vector_type(8)));
typedef u16   u16x4 __attribute__((ext_vector_type(4)));
typedef short s16x8 __attribute__((ext_vector_type(8)));
typedef float f32x4 __attribute__((ext_vector_type(4)));

#define MFMA16(a,b,c) __builtin_amdgcn_mfma_f32_16x16x32_bf16( \
    __builtin_bit_cast(s16x8,(a)), __builtin_bit_cast(s16x8,(b)), (c), 0, 0, 0)

static __device__ __forceinline__ u16 f2bf(float f) {
  __hip_bfloat16 h = __float2bfloat16(f);
  return *reinterpret_cast<u16*>(&h);
}
static __device__ __forceinline__ float bf2f(u16 v) {
  u32 t = ((u32)v) << 16;
  return __builtin_bit_cast(float, t);
}

#define NB   8
#define NS   2048
#define NF   256
#define NR   (NB*NS)          // 16384 rows

// vt swizzle: spreads both pr-clusters and a-clusters across banks.
#define VSWZ(f) ((((f) & 7) << 4) ^ ((((f) >> 3) & 3) << 5))

// ---------------- prep: qb = bf16(x*wc), xb = bf16(x), bvec = x.wb ---------
__global__ __launch_bounds__(256) void k_prep(const float* __restrict__ x,
                                              const float* __restrict__ attw,
                                              u16* __restrict__ qb,
                                              u16* __restrict__ xb,
                                              float* __restrict__ bvec) {
  const int lane = threadIdx.x & 63, w = threadIdx.x >> 6;
  const int row = blockIdx.x * 4 + w;                 // 0..16383
  const float4 xv = *reinterpret_cast<const float4*>(x + (size_t)row * NF + lane * 4);
  const float4 wc = *reinterpret_cast<const float4*>(attw + 2 * NF + lane * 4);
  const float4 wb = *reinterpret_cast<const float4*>(attw + NF + lane * 4);
  u16x4 q, xq;
  q[0] = f2bf(xv.x * wc.x); q[1] = f2bf(xv.y * wc.y);
  q[2] = f2bf(xv.z * wc.z); q[3] = f2bf(xv.w * wc.w);
  xq[0] = f2bf(xv.x); xq[1] = f2bf(xv.y); xq[2] = f2bf(xv.z); xq[3] = f2bf(xv.w);
  *reinterpret_cast<u16x4*>(qb + (size_t)row * NF + lane * 4) = q;
  *reinterpret_cast<u16x4*>(xb + (size_t)row * NF + lane * 4) = xq;
  float s = xv.x * wb.x + xv.y * wb.y + xv.z * wb.z + xv.w * wb.w;
  #pragma unroll
  for (int m = 1; m < 64; m <<= 1) s += __shfl_xor(s, m, 64);
  if (lane == 0) bvec[row] = s;
}

// ---------------- weight repack to B-fragment-linear bf16 ------------------
__global__ __launch_bounds__(64) void k_wrep(const float* __restrict__ zw,
                                             const float* __restrict__ rw,
                                             const float* __restrict__ fw,
                                             u16* __restrict__ wfrag) {
  const int lane = threadIdx.x & 63;
  const int idx = blockIdx.x;                   // 0..767
  const int w = idx >> 8, rem = idx & 255, ks = rem >> 4, nt = rem & 15;
  const float* W = (w == 0) ? zw : ((w == 1) ? rw : fw);
  const int n = lane & 15, g = lane >> 4;
  const float* src = W + (size_t)(nt * 16 + n) * 512 + ks * 32 + g * 8;
  u16x8 o;
  #pragma unroll
  for (int i = 0; i < 8; ++i) o[i] = f2bf(src[i]);
  *reinterpret_cast<u16x8*>(wfrag + ((size_t)(w * 256 + ks * 16 + nt) * 64 + lane) * 8) = o;
}

// ---------------- flash attention (R7) -------------------------------------
// grid 512 = (b = blk&7 [XCD], rest: itile = rest>>1, jh = rest&1).
// 512 thr = 8 waves: wr = w&3 -> 16-row quarter; wg = w>>2 -> j-sub-half
// (512 j, 8 jtt of 64). LDS 81920 B: vt[2 wg][256 f][64 j] bf16 swz (65536)
// + pl[8 wave][16 row][64 j] bf16 swz (16384). Merge aliases: Of->vt, ML->pl.
// Output: normalized bf16 partial (O/L) + (M,L) f32 per row.
__global__ __launch_bounds__(512, 1) void k_attn(const u16* __restrict__ qb,
                                                 const u16* __restrict__ xb,
                                                 const float* __restrict__ bvec,
                                                 u16* __restrict__ po0,
                                                 u16* __restrict__ po1,
                                                 float* __restrict__ mlp) {
  extern __shared__ u16 lds[];
  const int tid = threadIdx.x;
  const int w = tid >> 6, lane = tid & 63;
  const int wr = w & 3, wg = w >> 2;
  const int n = lane & 15, g = lane >> 4;
  const int b = blockIdx.x & 7, rest = blockIdx.x >> 3;
  const int itile = rest >> 1, jh = rest & 1;
  const int i0 = itile * 64;
  const size_t xbase = (size_t)b * (NS * NF);

  char* vt = reinterpret_cast<char*>(lds) + wg * 32768;
  char* pl = reinterpret_cast<char*>(lds) + 65536 + w * 2048;

  // Q fragments for this wave's 16 rows: 8 ks chunks
  u16x8 qf[8];
  {
    const u16* qrow = qb + xbase + (size_t)(i0 + 16 * wr + n) * NF + 8 * g;
    #pragma unroll
    for (int ks = 0; ks < 8; ++ks) qf[ks] = *reinterpret_cast<const u16x8*>(qrow + 32 * ks);
  }

  f32x4 O[16];
  #pragma unroll
  for (int nf = 0; nf < 16; ++nf) O[nf] = 0.f;
  float mrow[4], lrow[4];
  #pragma unroll
  for (int r = 0; r < 4; ++r) { mrow[r] = -__builtin_inff(); lrow[r] = 0.f; }

  for (int jtt = 0; jtt < 8; ++jtt) {
    const int j0 = jh * 1024 + wg * 512 + jtt * 64;
    // ---- stage V^T tile [256 f][64 j] (group = 256 threads, pair-packed) --
    {
      const int tg = tid & 255;
      const int pr = tg >> 3, a = tg & 7;            // j-pair 0..31, f-chunk
      #pragma unroll
      for (int it = 0; it < 4; ++it) {
        const int c = 8 * (a + 8 * it);
        const u16* r0 = xb + xbase + (size_t)(j0 + 2 * pr) * NF + c;
        u16x8 v0 = *reinterpret_cast<const u16x8*>(r0);
        u16x8 v1 = *reinterpret_cast<const u16x8*>(r0 + NF);
        #pragma unroll
        for (int i = 0; i < 8; ++i) {
          const int f = c + i;
          const u32 pk = (u32)v0[i] | ((u32)v1[i] << 16);
          const int byte = (f * 128 + 4 * pr) ^ VSWZ(f);
          *reinterpret_cast<u32*>(vt + byte) = pk;
        }
      }
    }
    __syncthreads();
    // ---- QK^T: 4 nf x 8 ks, K B-frags direct from global (L1/L2) ----------
    f32x4 sc[4];
    #pragma unroll
    for (int nf = 0; nf < 4; ++nf) {
      f32x4 acc = 0.f;
      const u16* krow = xb + xbase + (size_t)(j0 + 16 * nf + n) * NF + 8 * g;
      __builtin_amdgcn_s_setprio(1);
      #pragma unroll
      for (int ks = 0; ks < 8; ++ks) {
        u16x8 kf = *reinterpret_cast<const u16x8*>(krow + 32 * ks);
        acc = MFMA16(qf[ks], kf, acc);
      }
      __builtin_amdgcn_s_setprio(0);
      const float bv = bvec[b * NS + j0 + 16 * nf + n];
      #pragma unroll
      for (int r = 0; r < 4; ++r) sc[nf][r] = acc[r] + bv;
    }
    // ---- online softmax (rows = 4g+r, cols = n across 4 nf) ---------------
    float pmax[4];
    #pragma unroll
    for (int r = 0; r < 4; ++r) {
      float v = fmaxf(fmaxf(sc[0][r], sc[1][r]), fmaxf(sc[2][r], sc[3][r]));
      #pragma unroll
      for (int m = 1; m < 16; m <<= 1) v = fmaxf(v, __shfl_xor(v, m, 64));
      pmax[r] = v;
    }
    int needi = 0;
    #pragma unroll
    for (int r = 0; r < 4; ++r) needi |= (pmax[r] > mrow[r] + 8.0f) ? 1 : 0;
    if (__any(needi)) {               // T13 defer-max
      #pragma unroll
      for (int r = 0; r < 4; ++r) {
        const float mn = fmaxf(mrow[r], pmax[r]);
        const float scl = __expf(mrow[r] - mn);
        mrow[r] = mn; lrow[r] *= scl;
        #pragma unroll
        for (int nf = 0; nf < 16; ++nf) O[nf][r] *= scl;
      }
    }
    float p[4][4];
    #pragma unroll
    for (int nf = 0; nf < 4; ++nf)
      #pragma unroll
      for (int r = 0; r < 4; ++r) p[nf][r] = __expf(sc[nf][r] - mrow[r]);
    #pragma unroll
    for (int r = 0; r < 4; ++r) {
      float s = p[0][r] + p[1][r] + p[2][r] + p[3][r];
      #pragma unroll
      for (int m = 1; m < 16; m <<= 1) s += __shfl_xor(s, m, 64);
      lrow[r] += s;
    }
    // ---- P -> pl (swizzled [16 row][64 j]) -> A-frags ---------------------
    #pragma unroll
    for (int nf = 0; nf < 4; ++nf)
      #pragma unroll
      for (int r = 0; r < 4; ++r) {
        const int row = 4 * g + r, col = 16 * nf + n;
        const int byte = (row * 128 + 2 * col) ^ ((row & 7) << 4);
        *reinterpret_cast<u16*>(pl + byte) = f2bf(p[nf][r]);
      }
    // ---- PV: 2 ks2 x 16 nf ------------------------------------------------
    #pragma unroll
    for (int ks2 = 0; ks2 < 2; ++ks2) {
      const int pbyte = (n * 128 + 16 * g + 64 * ks2) ^ ((n & 7) << 4);
      u16x8 pa = *reinterpret_cast<const u16x8*>(pl + pbyte);
      __builtin_amdgcn_s_setprio(1);
      #pragma unroll
      for (int nf16 = 0; nf16 < 16; ++nf16) {
        const int f = 16 * nf16 + n;
        const int vbyte = (f * 128 + 16 * g + 64 * ks2) ^ VSWZ(f);
        u16x8 vf = *reinterpret_cast<const u16x8*>(vt + vbyte);
        O[nf16] = MFMA16(pa, vf, O[nf16]);
      }
      __builtin_amdgcn_s_setprio(0);
    }
    __syncthreads();
  }

  // ---- 2-way merge across wg; write normalized bf16 partial + (M,L) ------
  float* MLm = reinterpret_cast<float*>(reinterpret_cast<char*>(lds) + 65536); // aliases pl (dead)
  if (n == 0) {
    #pragma unroll
    for (int r = 0; r < 4; ++r) {
      const int row = 16 * wr + 4 * g + r;
      MLm[(wg * 64 + row) * 2]     = mrow[r];
      MLm[(wg * 64 + row) * 2 + 1] = lrow[r];
    }
  }
  __syncthreads();                                   // B1
  float fac[4], rL[4];
  #pragma unroll
  for (int r = 0; r < 4; ++r) {
    const int row = 16 * wr + 4 * g + r;
    const float m0 = MLm[row * 2],        l0 = MLm[row * 2 + 1];
    const float m1 = MLm[(64 + row) * 2], l1 = MLm[(64 + row) * 2 + 1];
    const float M = fmaxf(m0, m1);
    const float L = l0 * __expf(m0 - M) + l1 * __expf(m1 - M);
    fac[r] = __expf(mrow[r] - M);
    rL[r]  = 1.0f / L;
    if (wg == 0 && n == 0) {
      const size_t mb = ((size_t)((b * 32 + itile) * 2 + jh)) * 128 + row * 2;
      mlp[mb]     = M;
      mlp[mb + 1] = L;
    }
  }
  char* Of = reinterpret_cast<char*>(lds);           // aliases vt (dead)
  #define OBYTE(row, col) (((row) * 1024 + 4 * (col)) ^ (((row) & 12) << 3))
  if (wg == 1) {
    #pragma unroll
    for (int nf16 = 0; nf16 < 16; ++nf16)
      #pragma unroll
      for (int r = 0; r < 4; ++r) {
        const int row = 16 * wr + 4 * g + r, col = 16 * nf16 + n;
        *reinterpret_cast<float*>(Of + OBYTE(row, col)) = O[nf16][r] * fac[r];
      }
  }
  __syncthreads();                                   // B2
  if (wg == 0) {
    u16* po = jh ? po1 : po0;
    const size_t pbase = (size_t)(b * 32 + itile) * 64 * NF;
    #pragma unroll
    for (int nf16 = 0; nf16 < 16; ++nf16)
      #pragma unroll
      for (int r = 0; r < 4; ++r) {
        const int row = 16 * wr + 4 * g + r, col = 16 * nf16 + n;
        const float v = (O[nf16][r] * fac[r] +
            *reinterpret_cast<const float*>(Of + OBYTE(row, col))) * rL[r];
        po[pbase + (size_t)row * NF + col] = f2bf(v);
      }
  }
}

// ---------------- merge the two j-half partials (in place into po0) --------
__global__ __launch_bounds__(256) void k_amerge(const u16* __restrict__ po0,
                                                const u16* __restrict__ po1,
                                                const float* __restrict__ mlp,
                                                u16* __restrict__ attnb) {
  const int q = blockIdx.x * 256 + threadIdx.x;      // 0..1048575
  const int row = q >> 6;                            // 0..16383
  const int c4 = (q & 63) << 2;
  const int tile = row >> 6, rl = row & 63;
  const size_t m0b = ((size_t)(tile * 2 + 0)) * 128 + rl * 2;
  const size_t m1b = ((size_t)(tile * 2 + 1)) * 128 + rl * 2;
  const float M0 = mlp[m0b], L0 = mlp[m0b + 1];
  const float M1 = mlp[m1b], L1 = mlp[m1b + 1];
  const float M = fmaxf(M0, M1);
  float a0 = L0 * __expf(M0 - M), a1 = L1 * __expf(M1 - M);
  const float rT = 1.0f / (a0 + a1);
  a0 *= rT; a1 *= rT;
  const size_t off = (size_t)row * NF + c4;
  const u16x4 v0 = *reinterpret_cast<const u16x4*>(po0 + off);
  const u16x4 v1 = *reinterpret_cast<const u16x4*>(po1 + off);
  u16x4 o;
  #pragma unroll
  for (int i = 0; i < 4; ++i) o[i] = f2bf(bf2f(v0[i]) * a0 + bf2f(v1[i]) * a1);
  *reinterpret_cast<u16x4*>(attnb + off) = o;
}

// ---------------- fused gate GEMMs + epilogue ------------------------------
// grid 1024 x 256 thr: block = 16 rows; wave w -> col quarter (nt = 4w+nt2).
__global__ __launch_bounds__(256, 4) void k_gate(const u16* __restrict__ xb,
                                                 const u16* __restrict__ attnb,
                                                 const float* __restrict__ x,
                                                 const float* __restrict__ zb,
                                                 const float* __restrict__ rb,
                                                 const float* __restrict__ fb,
                                                 const u16* __restrict__ wfrag,
                                                 float* __restrict__ out) {
  const int tid = threadIdx.x, w = tid >> 6, lane = tid & 63;
  const int m0 = blockIdx.x * 16;
  const int n = lane & 15, g = lane >> 4;

  u16x8 af[16];
  {
    const int row = m0 + n;
    const u16* xr = xb + (size_t)row * NF + 8 * g;
    #pragma unroll
    for (int ks = 0; ks < 8; ++ks) af[ks] = *reinterpret_cast<const u16x8*>(xr + 32 * ks);
    const u16* ar = attnb + (size_t)row * NF + 8 * g;
    #pragma unroll
    for (int ks = 0; ks < 8; ++ks) af[8 + ks] = *reinterpret_cast<const u16x8*>(ar + 32 * ks);
  }
  #pragma unroll
  for (int nt2 = 0; nt2 < 4; ++nt2) {
    const int nt = 4 * w + nt2;
    const int col = 16 * nt + n;
    f32x4 za = zb[col], ra = rb[col], fa = fb[col];
    #pragma unroll
    for (int ks = 0; ks < 16; ++ks) {
      const size_t base = ((size_t)(ks * 16 + nt) * 64 + lane) * 8;
      u16x8 bz  = *reinterpret_cast<const u16x8*>(wfrag + base);
      u16x8 br  = *reinterpret_cast<const u16x8*>(wfrag + (size_t)256 * 64 * 8 + base);
      u16x8 bff = *reinterpret_cast<const u16x8*>(wfrag + (size_t)512 * 64 * 8 + base);
      za = MFMA16(af[ks], bz, za);
      ra = MFMA16(af[ks], br, ra);
      fa = MFMA16(af[ks], bff, fa);
    }
    #pragma unroll
    for (int r = 0; r < 4; ++r) {
      const int row = m0 + 4 * g + r;
      const float xv = x[(size_t)row * NF + col];
      const float zv = 2.f / (1.f + __expf(-2.f * za[r])) - 1.f;  // tanh
      const float rv = 1.f / (1.f + __expf(-ra[r]));
      const float fv = 1.f / (1.f + __expf(-fa[r]));
      out[(size_t)row * NF + col] = rv * xv + fv * zv;
    }
  }
}

// ---------------------------------------------------------------------------
extern "C" void kernel_launch(void* const* d_in, const int* in_sizes, int n_in,
                              void* d_out, int out_size, void* d_ws, size_t ws_size,
                              hipStream_t stream) {
  const float* x    = (const float*)d_in[0];
  const float* attw = (const float*)d_in[1];
  const float* zw   = (const float*)d_in[2];
  const float* zb   = (const float*)d_in[3];
  const float* rw   = (const float*)d_in[4];
  const float* rb   = (const float*)d_in[5];
  const float* fw   = (const float*)d_in[6];
  const float* fb   = (const float*)d_in[7];
  float* out = (float*)d_out;

  char* ws = (char*)d_ws;
  u16*   qb    = (u16*)(ws);                       //  8 MB
  u16*   xbb   = (u16*)(ws + 8388608);             //  8 MB
  u16*   po0   = (u16*)(ws + 16777216);            //  8 MB (partial 0 / final attnb)
  float* bvec  = (float*)(ws + 25165824);          // 64 KB
  u16*   wfrag = (u16*)(ws + 25231360);            // 768 KB -> ends 26017792
  u16*   po1   = (u16*)(ws + 26214400);            //  8 MB (partial 1)
  float* mlp   = (float*)(ws + 34603008);          // 256 KB -> ends ~33.3 MB

  (void)hipFuncSetAttribute((const void*)k_attn,
      hipFuncAttributeMaxDynamicSharedMemorySize, 81920);

  k_prep<<<NR / 4, 256, 0, stream>>>(x, attw, qb, xbb, bvec);
  k_wrep<<<768, 64, 0, stream>>>(zw, rw, fw, wfrag);
  k_attn<<<512, 512, 81920, stream>>>(qb, xbb, bvec, po0, po1, mlp);
  k_amerge<<<4096, 256, 0, stream>>>(po0, po1, mlp, po0);
  k_gate<<<1024, 256, 0, stream>>>(xbb, po0, x, zb, rb, fb, wfrag, out);
}